// Round 3
// baseline (143.029 us; speedup 1.0000x reference)
//
#include <hip/hip_runtime.h>
#include <hip/hip_bf16.h>
#include <cstdint>

// N=2, L=2048, H=8, d=64, D=512. Inputs/outputs f32; features bf16 + MFMA.

typedef __bf16 bf16x8 __attribute__((ext_vector_type(8)));
typedef float f32x16 __attribute__((ext_vector_type(16)));
typedef unsigned short u16x8 __attribute__((ext_vector_type(8)));

__device__ __forceinline__ unsigned short f2bfu(float f) {
    uint32_t u = __float_as_uint(f);
    uint32_t r = (u + 0x7fffu + ((u >> 16) & 1u)) >> 16;
    return (unsigned short)r;
}
__device__ __forceinline__ uint32_t cvt2(float a, float b) {
    __hip_bfloat162 h = __float22bfloat162_rn(make_float2(a, b));
    return *reinterpret_cast<uint32_t*>(&h);
}
__device__ __forceinline__ float softplusf(float x) {
    // fast: log(1+e^-|x|) via __logf; error ~1e-6 rel, far below bf16 ulp.
    return fmaxf(x, 0.f) + __logf(1.f + __expf(-fabsf(x)));
}

// ---------------------------------------------------------------------------
// cvt: one-shot f32 -> bf16 of query/key/Wq/Wk/Wv. ~30 MB traffic, ~5 us.
// Removes per-tile f32 loads + cvt VALU from proj's hot loop; halves the
// redundant L2/L3 tile traffic that bounded proj (~293 MB @ ~7 TB/s = 42 us).
// ---------------------------------------------------------------------------
__global__ __launch_bounds__(256) void cvt_kernel(
    const float* __restrict__ query, const float* __restrict__ key,
    const float* __restrict__ Wq, const float* __restrict__ Wk,
    const float* __restrict__ Wv,
    unsigned short* __restrict__ Xqb, unsigned short* __restrict__ Xkb,
    unsigned short* __restrict__ Wqb, unsigned short* __restrict__ Wkb,
    unsigned short* __restrict__ Wvb)
{
    const int z = blockIdx.z;
    const float* src;
    unsigned short* dst;
    int n8;   // number of 8-element groups
    if (z == 0)      { src = query; dst = Xqb; n8 = 4096 * 512 / 8; }
    else if (z == 1) { src = key;   dst = Xkb; n8 = 4096 * 512 / 8; }
    else if (z == 2) { src = Wq;    dst = Wqb; n8 = 512 * 512 / 8;  }
    else if (z == 3) { src = Wk;    dst = Wkb; n8 = 512 * 512 / 8;  }
    else             { src = Wv;    dst = Wvb; n8 = 512 * 512 / 8;  }
    int idx = blockIdx.x * 256 + threadIdx.x;
    if (idx >= n8) return;
    const float4* s = (const float4*)src + (size_t)idx * 2;
    float4 a = s[0], b = s[1];
    uint4 o;
    o.x = cvt2(a.x, a.y); o.y = cvt2(a.z, a.w);
    o.z = cvt2(b.x, b.y); o.w = cvt2(b.z, b.w);
    *(uint4*)&dst[(size_t)idx * 8] = o;
}

// ---------------------------------------------------------------------------
// proj v2: C[m][c] = X[m][:] . W[c][:]  (4096x512x512 per mode), bf16 inputs,
// 128x128 tiles (was 64x128 f32). Redundant cache traffic per mode drops from
// gx4*8.4MB + gy64*1.0MB = 98 MB to gx4*4.2 + gy32*0.5 = 33 MB (3x), and the
// in-loop f32->bf16 cvt VALU is gone. 384 blocks. Per wave: 64x64 out =
// 2x2 f32x16 accs (64 AGPR) -- safely below the round-1 spill cliff.
// mode 0 -> Af[nh][l][128]; mode 1 -> Bf[nh][l][128]; mode 2 -> Vf[nh][dd][l]
// ---------------------------------------------------------------------------
__global__ __launch_bounds__(256) void proj_kernel(
    const unsigned short* __restrict__ Xqb, const unsigned short* __restrict__ Xkb,
    const unsigned short* __restrict__ Wqb, const unsigned short* __restrict__ Wkb,
    const unsigned short* __restrict__ Wvb, const float* __restrict__ coef,
    const float* __restrict__ posw, const float* __restrict__ posb,
    unsigned short* __restrict__ Af, unsigned short* __restrict__ Bf,
    unsigned short* __restrict__ Vf)
{
    const int mode = blockIdx.z;
    const int c0 = blockIdx.x * 128;   // 4 tiles
    const int m0 = blockIdx.y * 128;   // 32 tiles
    const unsigned short* X = (mode == 0) ? Xqb : Xkb;
    const unsigned short* W = (mode == 0) ? Wqb : (mode == 1 ? Wkb : Wvb);

    __shared__ __align__(16) char smem[128 * 72 * 2 * 2];  // 36864 B
    unsigned short* Xs = (unsigned short*)smem;                   // [128][72]
    unsigned short* Ws = (unsigned short*)(smem + 128 * 72 * 2);  // [128][72]

    const int t = threadIdx.x;
    const int lane = t & 63, wv = t >> 6;
    const int lm = lane & 31, half = lane >> 5;
    const int wrow = wv >> 1, wcol = wv & 1;

    f32x16 acc[2][2] = {};

    // register double-buffered staging: 128 rows x 64 cols bf16 = 1024 chunks
    // of u16x8; 4 chunks/thread for X and for W.
    u16x8 px[4], pw[4];
    {
#pragma unroll
        for (int it = 0; it < 4; ++it) {
            int cid = t + it * 256, row = cid >> 3, seg = cid & 7;
            px[it] = *(const u16x8*)&X[(size_t)(m0 + row) * 512 + seg * 8];
            pw[it] = *(const u16x8*)&W[(size_t)(c0 + row) * 512 + seg * 8];
        }
    }

    for (int kt = 0; kt < 8; ++kt) {
        __syncthreads();
#pragma unroll
        for (int it = 0; it < 4; ++it) {
            int cid = t + it * 256, row = cid >> 3, seg = cid & 7;
            *(u16x8*)&Xs[row * 72 + seg * 8] = px[it];
            *(u16x8*)&Ws[row * 72 + seg * 8] = pw[it];
        }
        __syncthreads();
        if (kt < 7) {
            int ko = (kt + 1) * 64;
#pragma unroll
            for (int it = 0; it < 4; ++it) {
                int cid = t + it * 256, row = cid >> 3, seg = cid & 7;
                px[it] = *(const u16x8*)&X[(size_t)(m0 + row) * 512 + ko + seg * 8];
                pw[it] = *(const u16x8*)&W[(size_t)(c0 + row) * 512 + ko + seg * 8];
            }
        }
        const unsigned short* ab = &Xs[(64 * wrow + lm) * 72 + half * 8];
        const unsigned short* bb = &Ws[(64 * wcol + lm) * 72 + half * 8];
        __builtin_amdgcn_s_setprio(1);
#pragma unroll
        for (int ks = 0; ks < 4; ++ks) {
            bf16x8 a0 = *(const bf16x8*)(ab + ks * 16);
            bf16x8 a1 = *(const bf16x8*)(ab + 32 * 72 + ks * 16);
            bf16x8 b0 = *(const bf16x8*)(bb + ks * 16);
            bf16x8 b1 = *(const bf16x8*)(bb + 32 * 72 + ks * 16);
            acc[0][0] = __builtin_amdgcn_mfma_f32_32x32x16_bf16(a0, b0, acc[0][0], 0, 0, 0);
            acc[0][1] = __builtin_amdgcn_mfma_f32_32x32x16_bf16(a0, b1, acc[0][1], 0, 0, 0);
            acc[1][0] = __builtin_amdgcn_mfma_f32_32x32x16_bf16(a1, b0, acc[1][0], 0, 0, 0);
            acc[1][1] = __builtin_amdgcn_mfma_f32_32x32x16_bf16(a1, b1, acc[1][1], 0, 0, 0);
        }
        __builtin_amdgcn_s_setprio(0);
    }

    if (mode != 2) {
        unsigned short* Feat = (mode == 0) ? Af : Bf;
#pragma unroll
        for (int i = 0; i < 2; ++i)
#pragma unroll
        for (int j = 0; j < 2; ++j)
#pragma unroll
        for (int r = 0; r < 16; ++r) {
            int rl = (r & 3) + 8 * (r >> 2) + 4 * half;
            int m = m0 + 64 * wrow + 32 * i + rl;
            int c = c0 + 64 * wcol + 32 * j + lm;
            int n = m >> 11, l = m & 2047;
            int h = c >> 6, jj = c & 63;
            float ang = (float)l * posw[c] + ((mode == 0) ? posb[c] : 0.f);
            float sn, cs; __sincosf(ang, &sn, &cs);
            float v = softplusf(acc[i][j][r]);
            if (mode == 1) v *= coef[c];
            size_t base = ((size_t)(n * 8 + h) * 2048 + l) * 128 + jj;
            Feat[base]      = f2bfu(v * cs);
            Feat[base + 64] = f2bfu(v * sn);
        }
    } else {
        // transpose through LDS; per-wave private 32x34 f32 buffer overlays
        // smem (4 waves * 32*34*4 = 17408 B <= 36864 B). Within-wave
        // write->read needs no barrier (lgkmcnt ordering); one entry sync
        // protects the Xs/Ws overlay vs other waves' final MFMA reads.
        float* tb = (float*)smem;
        float* tbw = tb + wv * (32 * 34);
        __syncthreads();
#pragma unroll
        for (int i = 0; i < 2; ++i)
#pragma unroll
        for (int j = 0; j < 2; ++j) {
#pragma unroll
            for (int r = 0; r < 16; ++r) {
                int rl = (r & 3) + 8 * (r >> 2) + 4 * half;
                tbw[lm * 34 + rl] = acc[i][j][r];
            }
            int mb = m0 + 64 * wrow + 32 * i;
            int n = mb >> 11, l0 = mb & 2047;
#pragma unroll
            for (int rep = 0; rep < 16; ++rep) {
                int cl = rep * 2 + half;
                float v = tbw[cl * 34 + lm];
                int c = c0 + 64 * wcol + 32 * j + cl;
                int h = c >> 6, dd = c & 63;
                Vf[((size_t)(n * 8 + h) * 64 + dd) * 2048 + l0 + lm] = f2bfu(v);
            }
        }
    }
}

// ---------------------------------------------------------------------------
// attn: round-0 structure (512 blocks, complementary pairing, in-kernel
// divide) + free setprio wraps. Split-k removed: round-2 A/B showed 2x grid
// changed attn dur by 0 (43.0 vs 43.5) -- not wave-parallelism-bound.
// ---------------------------------------------------------------------------
__global__ __launch_bounds__(256) void attn_kernel(
    const unsigned short* __restrict__ Af, const unsigned short* __restrict__ Bf,
    const unsigned short* __restrict__ Vf, float* __restrict__ out)
{
    const int bx = blockIdx.x;
    const int nh = bx & 15;
    const int p  = bx >> 4;
    const int qq = (p < 16) ? p : 47 - p;   // bx and bx+256 complementary
    const int q0 = qq * 64;

    __shared__ unsigned short Bs[64 * 136];   // K-features [k][128+pad]; A-stage at init
    __shared__ unsigned short Ss[64 * 72];    // S tile [q][k+pad] bf16
    __shared__ unsigned short Vs[64 * 72];    // V [dd][k]
    __shared__ float zf[64];

    const int t = threadIdx.x;
    const int lane = t & 63, wv = t >> 6;
    const int lm = lane & 31, half = lane >> 5;
    const int wrow = wv >> 1, wcol = wv & 1;
    const int n = nh >> 3, h = nh & 7;

    const unsigned short* Ah = Af + (size_t)nh * 2048 * 128;
    const unsigned short* Bh = Bf + (size_t)nh * 2048 * 128;
    const unsigned short* Vh = Vf + (size_t)nh * 64 * 2048;

    // stage Q-features through Bs once, pull A-fragments into registers
#pragma unroll
    for (int it = 0; it < 4; ++it) {
        int cid = t + it * 256, row = cid >> 4, off = (cid & 15) << 3;
        *(u16x8*)&Bs[row * 136 + off] = *(const u16x8*)&Ah[(size_t)(q0 + row) * 128 + off];
    }
    if (t < 64) zf[t] = 0.f;
    __syncthreads();
    bf16x8 afrag[8];
    {
        const unsigned short* ab = &Bs[(32 * wrow + lm) * 136 + half * 8];
#pragma unroll
        for (int c = 0; c < 8; ++c) afrag[c] = *(const bf16x8*)(ab + c * 16);
    }

    f32x16 oacc = {};
    float zp[16];
#pragma unroll
    for (int r = 0; r < 16; ++r) zp[r] = 0.f;

    u16x8 pb[4], pv[2];
#pragma unroll
    for (int it = 0; it < 4; ++it) {
        int cid = t + it * 256, row = cid >> 4, off = (cid & 15) << 3;
        pb[it] = *(const u16x8*)&Bh[(size_t)row * 128 + off];
    }
#pragma unroll
    for (int it = 0; it < 2; ++it) {
        int cid = t + it * 256, row = cid >> 3, off = (cid & 7) << 3;
        pv[it] = *(const u16x8*)&Vh[(size_t)row * 2048 + off];
    }

    for (int kt = 0; kt <= qq; ++kt) {
        __syncthreads();   // b1: afrag reads done (kt=0); prev O-reads of Ss/Vs done
#pragma unroll
        for (int it = 0; it < 4; ++it) {
            int cid = t + it * 256, row = cid >> 4, off = (cid & 15) << 3;
            *(u16x8*)&Bs[row * 136 + off] = pb[it];
        }
#pragma unroll
        for (int it = 0; it < 2; ++it) {
            int cid = t + it * 256, row = cid >> 3, off = (cid & 7) << 3;
            *(u16x8*)&Vs[row * 72 + off] = pv[it];
        }
        __syncthreads();   // b2: Bs/Vs visible
        if (kt < qq) {
            int k1 = (kt + 1) * 64;
#pragma unroll
            for (int it = 0; it < 4; ++it) {
                int cid = t + it * 256, row = cid >> 4, off = (cid & 15) << 3;
                pb[it] = *(const u16x8*)&Bh[(size_t)(k1 + row) * 128 + off];
            }
#pragma unroll
            for (int it = 0; it < 2; ++it) {
                int cid = t + it * 256, row = cid >> 3, off = (cid & 7) << 3;
                pv[it] = *(const u16x8*)&Vh[(size_t)row * 2048 + k1 + off];
            }
        }

        f32x16 sacc = {};
        const unsigned short* bbase = &Bs[(32 * wcol + lm) * 136 + half * 8];
        __builtin_amdgcn_s_setprio(1);
#pragma unroll
        for (int ks = 0; ks < 8; ++ks) {
            bf16x8 b = *(const bf16x8*)(bbase + ks * 16);
            sacc = __builtin_amdgcn_mfma_f32_32x32x16_bf16(afrag[ks], b, sacc, 0, 0, 0);
        }
        __builtin_amdgcn_s_setprio(0);
        if (kt == qq) {
#pragma unroll
            for (int r = 0; r < 16; ++r) {
                int rl = (r & 3) + 8 * (r >> 2) + 4 * half;
                if ((32 * wcol + lm) > (32 * wrow + rl)) sacc[r] = 0.f;
            }
        }
#pragma unroll
        for (int r = 0; r < 16; ++r) zp[r] += fabsf(sacc[r]);

        // writeback S -> Ss (own data; ordered vs prev O-reads by b1/b2)
#pragma unroll
        for (int r = 0; r < 16; ++r) {
            int rl = (r & 3) + 8 * (r >> 2) + 4 * half;
            Ss[(32 * wrow + rl) * 72 + 32 * wcol + lm] = f2bfu(sacc[r]);
        }
        __syncthreads();   // b3: Ss visible

        const unsigned short* sbase = &Ss[(32 * wrow + lm) * 72 + half * 8];
        const unsigned short* vbase = &Vs[(32 * wcol + lm) * 72 + half * 8];
        __builtin_amdgcn_s_setprio(1);
#pragma unroll
        for (int kc = 0; kc < 4; ++kc) {
            bf16x8 a = *(const bf16x8*)(sbase + kc * 16);
            bf16x8 b = *(const bf16x8*)(vbase + kc * 16);
            oacc = __builtin_amdgcn_mfma_f32_32x32x16_bf16(a, b, oacc, 0, 0, 0);
        }
        __builtin_amdgcn_s_setprio(0);
    }

    // reduce z: shuffle over 32-lane halves, then LDS atomics across waves
    __syncthreads();
#pragma unroll
    for (int r = 0; r < 16; ++r) {
        float z = zp[r];
        z += __shfl_xor(z, 1);
        z += __shfl_xor(z, 2);
        z += __shfl_xor(z, 4);
        z += __shfl_xor(z, 8);
        z += __shfl_xor(z, 16);
        if (lm == 0) {
            int rl = (r & 3) + 8 * (r >> 2) + 4 * half;
            atomicAdd(&zf[32 * wrow + rl], z);
        }
    }
    __syncthreads();
#pragma unroll
    for (int r = 0; r < 16; ++r) {
        int rl = (r & 3) + 8 * (r >> 2) + 4 * half;
        int q = q0 + 32 * wrow + rl;
        float invz = 1.f / zf[32 * wrow + rl];
        out[((size_t)(n * 2048 + q)) * 512 + h * 64 + 32 * wcol + lm] = oacc[r] * invz;
    }
}

extern "C" void kernel_launch(void* const* d_in, const int* in_sizes, int n_in,
                              void* d_out, int out_size, void* d_ws, size_t ws_size,
                              hipStream_t stream) {
    (void)in_sizes; (void)n_in; (void)out_size; (void)ws_size;
    const float* query = (const float*)d_in[0];
    const float* key   = (const float*)d_in[1];
    const float* Wq    = (const float*)d_in[2];
    const float* Wk    = (const float*)d_in[3];
    const float* Wv    = (const float*)d_in[4];
    const float* coef  = (const float*)d_in[5];
    const float* posw  = (const float*)d_in[6];
    const float* posb  = (const float*)d_in[7];

    unsigned short* Af  = (unsigned short*)d_ws;            // 8 MiB
    unsigned short* Bf  = Af + (size_t)16 * 2048 * 128;     // 8 MiB
    unsigned short* Vf  = Bf + (size_t)16 * 2048 * 128;     // 4 MiB
    unsigned short* Xqb = Vf + (size_t)16 * 64 * 2048;      // 4 MiB
    unsigned short* Xkb = Xqb + (size_t)4096 * 512;         // 4 MiB
    unsigned short* Wqb = Xkb + (size_t)4096 * 512;         // 0.5 MiB
    unsigned short* Wkb = Wqb + (size_t)512 * 512;          // 0.5 MiB
    unsigned short* Wvb = Wkb + (size_t)512 * 512;          // 0.5 MiB
    // total workspace: ~29 MiB

    cvt_kernel<<<dim3(1024, 1, 5), 256, 0, stream>>>(
        query, key, Wq, Wk, Wv, Xqb, Xkb, Wqb, Wkb, Wvb);
    proj_kernel<<<dim3(4, 32, 3), 256, 0, stream>>>(
        Xqb, Xkb, Wqb, Wkb, Wvb, coef, posw, posb, Af, Bf, Vf);
    attn_kernel<<<dim3(512), 256, 0, stream>>>(
        Af, Bf, Vf, (float*)d_out);
}

// Round 4
// 133.002 us; speedup vs baseline: 1.0754x; 1.0754x over previous
//
#include <hip/hip_runtime.h>
#include <hip/hip_bf16.h>
#include <cstdint>

// N=2, L=2048, H=8, d=64, D=512. Inputs/outputs f32; features bf16 + MFMA.

typedef __bf16 bf16x8 __attribute__((ext_vector_type(8)));
typedef float f32x16 __attribute__((ext_vector_type(16)));
typedef unsigned short u16x8 __attribute__((ext_vector_type(8)));
typedef uint32_t u32x4 __attribute__((ext_vector_type(4)));

__device__ __forceinline__ unsigned short f2bfu(float f) {
    uint32_t u = __float_as_uint(f);
    uint32_t r = (u + 0x7fffu + ((u >> 16) & 1u)) >> 16;
    return (unsigned short)r;
}
__device__ __forceinline__ uint32_t cvt2(float a, float b) {
    __hip_bfloat162 h = __float22bfloat162_rn(make_float2(a, b));
    return *reinterpret_cast<uint32_t*>(&h);
}
__device__ __forceinline__ float softplusf(float x) {
    return fmaxf(x, 0.f) + __logf(1.f + __expf(-fabsf(x)));
}
// pack two f32 -> one u32 of 2 bf16 (src0 -> low half)
__device__ __forceinline__ uint32_t pkbf(float a, float b) {
    uint32_t d;
    asm("v_cvt_pk_bf16_f32 %0, %1, %2" : "=v"(d) : "v"(a), "v"(b));
    return d;
}
// v_permlane32_swap_b32: a[l>=32] <-> b[l-32]  (swap a's hi lanes with b's lo lanes)
__device__ __forceinline__ void plswap(uint32_t& a, uint32_t& b) {
    asm volatile("v_permlane32_swap_b32 %0, %1" : "+v"(a), "+v"(b));
}

// ---------------------------------------------------------------------------
// cvt: one-shot f32 -> bf16 of query/key/Wq/Wk/Wv. UNCHANGED.
// ---------------------------------------------------------------------------
__global__ __launch_bounds__(256) void cvt_kernel(
    const float* __restrict__ query, const float* __restrict__ key,
    const float* __restrict__ Wq, const float* __restrict__ Wk,
    const float* __restrict__ Wv,
    unsigned short* __restrict__ Xqb, unsigned short* __restrict__ Xkb,
    unsigned short* __restrict__ Wqb, unsigned short* __restrict__ Wkb,
    unsigned short* __restrict__ Wvb)
{
    const int z = blockIdx.z;
    const float* src;
    unsigned short* dst;
    int n8;
    if (z == 0)      { src = query; dst = Xqb; n8 = 4096 * 512 / 8; }
    else if (z == 1) { src = key;   dst = Xkb; n8 = 4096 * 512 / 8; }
    else if (z == 2) { src = Wq;    dst = Wqb; n8 = 512 * 512 / 8;  }
    else if (z == 3) { src = Wk;    dst = Wkb; n8 = 512 * 512 / 8;  }
    else             { src = Wv;    dst = Wvb; n8 = 512 * 512 / 8;  }
    int idx = blockIdx.x * 256 + threadIdx.x;
    if (idx >= n8) return;
    const float4* s = (const float4*)src + (size_t)idx * 2;
    float4 a = s[0], b = s[1];
    uint4 o;
    o.x = cvt2(a.x, a.y); o.y = cvt2(a.z, a.w);
    o.z = cvt2(b.x, b.y); o.w = cvt2(b.z, b.w);
    *(uint4*)&dst[(size_t)idx * 8] = o;
}

// ---------------------------------------------------------------------------
// proj v2: bf16 inputs, 128x128 tiles. UNCHANGED this round (needs counters
// before further work; round-3 estimate ~35-40us, L3-BW theory refuted).
// ---------------------------------------------------------------------------
__global__ __launch_bounds__(256) void proj_kernel(
    const unsigned short* __restrict__ Xqb, const unsigned short* __restrict__ Xkb,
    const unsigned short* __restrict__ Wqb, const unsigned short* __restrict__ Wkb,
    const unsigned short* __restrict__ Wvb, const float* __restrict__ coef,
    const float* __restrict__ posw, const float* __restrict__ posb,
    unsigned short* __restrict__ Af, unsigned short* __restrict__ Bf,
    unsigned short* __restrict__ Vf)
{
    const int mode = blockIdx.z;
    const int c0 = blockIdx.x * 128;
    const int m0 = blockIdx.y * 128;
    const unsigned short* X = (mode == 0) ? Xqb : Xkb;
    const unsigned short* W = (mode == 0) ? Wqb : (mode == 1 ? Wkb : Wvb);

    __shared__ __align__(16) char smem[128 * 72 * 2 * 2];
    unsigned short* Xs = (unsigned short*)smem;
    unsigned short* Ws = (unsigned short*)(smem + 128 * 72 * 2);

    const int t = threadIdx.x;
    const int lane = t & 63, wv = t >> 6;
    const int lm = lane & 31, half = lane >> 5;
    const int wrow = wv >> 1, wcol = wv & 1;

    f32x16 acc[2][2] = {};

    u16x8 px[4], pw[4];
    {
#pragma unroll
        for (int it = 0; it < 4; ++it) {
            int cid = t + it * 256, row = cid >> 3, seg = cid & 7;
            px[it] = *(const u16x8*)&X[(size_t)(m0 + row) * 512 + seg * 8];
            pw[it] = *(const u16x8*)&W[(size_t)(c0 + row) * 512 + seg * 8];
        }
    }

    for (int kt = 0; kt < 8; ++kt) {
        __syncthreads();
#pragma unroll
        for (int it = 0; it < 4; ++it) {
            int cid = t + it * 256, row = cid >> 3, seg = cid & 7;
            *(u16x8*)&Xs[row * 72 + seg * 8] = px[it];
            *(u16x8*)&Ws[row * 72 + seg * 8] = pw[it];
        }
        __syncthreads();
        if (kt < 7) {
            int ko = (kt + 1) * 64;
#pragma unroll
            for (int it = 0; it < 4; ++it) {
                int cid = t + it * 256, row = cid >> 3, seg = cid & 7;
                px[it] = *(const u16x8*)&X[(size_t)(m0 + row) * 512 + ko + seg * 8];
                pw[it] = *(const u16x8*)&W[(size_t)(c0 + row) * 512 + ko + seg * 8];
            }
        }
        const unsigned short* ab = &Xs[(64 * wrow + lm) * 72 + half * 8];
        const unsigned short* bb = &Ws[(64 * wcol + lm) * 72 + half * 8];
        __builtin_amdgcn_s_setprio(1);
#pragma unroll
        for (int ks = 0; ks < 4; ++ks) {
            bf16x8 a0 = *(const bf16x8*)(ab + ks * 16);
            bf16x8 a1 = *(const bf16x8*)(ab + 32 * 72 + ks * 16);
            bf16x8 b0 = *(const bf16x8*)(bb + ks * 16);
            bf16x8 b1 = *(const bf16x8*)(bb + 32 * 72 + ks * 16);
            acc[0][0] = __builtin_amdgcn_mfma_f32_32x32x16_bf16(a0, b0, acc[0][0], 0, 0, 0);
            acc[0][1] = __builtin_amdgcn_mfma_f32_32x32x16_bf16(a0, b1, acc[0][1], 0, 0, 0);
            acc[1][0] = __builtin_amdgcn_mfma_f32_32x32x16_bf16(a1, b0, acc[1][0], 0, 0, 0);
            acc[1][1] = __builtin_amdgcn_mfma_f32_32x32x16_bf16(a1, b1, acc[1][1], 0, 0, 0);
        }
        __builtin_amdgcn_s_setprio(0);
    }

    if (mode != 2) {
        unsigned short* Feat = (mode == 0) ? Af : Bf;
#pragma unroll
        for (int i = 0; i < 2; ++i)
#pragma unroll
        for (int j = 0; j < 2; ++j)
#pragma unroll
        for (int r = 0; r < 16; ++r) {
            int rl = (r & 3) + 8 * (r >> 2) + 4 * half;
            int m = m0 + 64 * wrow + 32 * i + rl;
            int c = c0 + 64 * wcol + 32 * j + lm;
            int n = m >> 11, l = m & 2047;
            int h = c >> 6, jj = c & 63;
            float ang = (float)l * posw[c] + ((mode == 0) ? posb[c] : 0.f);
            float sn, cs; __sincosf(ang, &sn, &cs);
            float v = softplusf(acc[i][j][r]);
            if (mode == 1) v *= coef[c];
            size_t base = ((size_t)(n * 8 + h) * 2048 + l) * 128 + jj;
            Feat[base]      = f2bfu(v * cs);
            Feat[base + 64] = f2bfu(v * sn);
        }
    } else {
        float* tb = (float*)smem;
        float* tbw = tb + wv * (32 * 34);
        __syncthreads();
#pragma unroll
        for (int i = 0; i < 2; ++i)
#pragma unroll
        for (int j = 0; j < 2; ++j) {
#pragma unroll
            for (int r = 0; r < 16; ++r) {
                int rl = (r & 3) + 8 * (r >> 2) + 4 * half;
                tbw[lm * 34 + rl] = acc[i][j][r];
            }
            int mb = m0 + 64 * wrow + 32 * i;
            int n = mb >> 11, l0 = mb & 2047;
#pragma unroll
            for (int rep = 0; rep < 16; ++rep) {
                int cl = rep * 2 + half;
                float v = tbw[cl * 34 + lm];
                int c = c0 + 64 * wcol + 32 * j + cl;
                int h = c >> 6, dd = c & 63;
                Vf[((size_t)(n * 8 + h) * 64 + dd) * 2048 + l0 + lm] = f2bfu(v);
            }
        }
    }
}

// ---------------------------------------------------------------------------
// attn v2: swapped QK^T (T12). Each wave = (qb,kb) quadrant of the 64x64 tile.
// sacc = mfma(Kfrag, Qfrag) -> S^T with q in LANE dim: P-row is lane-local.
// cvt_pk_bf16 + permlane32_swap build PV A-frags IN REGISTERS -- eliminates
// the S->bf16->LDS->reread round-trip (16 ds_write_b16 + 8 ds_read_b128 +
// 1 barrier + 64 VALU per tile). Each wave accumulates a k-partial O over
// both dd halves; one end-of-kernel LDS merge (overlaying Bs) combines.
// Per tile: 18 LDS ops (was 38), 2 barriers (was 3), ~55 VALU (was ~112).
// z: per-lane scalar (q = lane), one atomicAdd per lane at the end.
// ---------------------------------------------------------------------------
__global__ __launch_bounds__(256) void attn_kernel(
    const unsigned short* __restrict__ Af, const unsigned short* __restrict__ Bf,
    const unsigned short* __restrict__ Vf, float* __restrict__ out)
{
    const int bx = blockIdx.x;
    const int nh = bx & 15;
    const int p  = bx >> 4;
    const int qq = (p < 16) ? p : 47 - p;   // bx and bx+256 complementary
    const int q0 = qq * 64;

    __shared__ unsigned short Bs[64 * 136];   // K-features [k][128+pad]; Q-stage at init; O-merge overlay at end
    __shared__ unsigned short Vs[64 * 72];    // V [dd][k]
    __shared__ float zf[64];

    const int t = threadIdx.x;
    const int lane = t & 63, wv = t >> 6;
    const int lm = lane & 31, half = lane >> 5;
    const int qb = wv >> 1, kb = wv & 1;
    const int n = nh >> 3, h = nh & 7;

    const unsigned short* Ah = Af + (size_t)nh * 2048 * 128;
    const unsigned short* Bh = Bf + (size_t)nh * 2048 * 128;
    const unsigned short* Vh = Vf + (size_t)nh * 64 * 2048;

    // stage Q rows through Bs once; pull Q-fragments (B-operand, rows q) to regs
#pragma unroll
    for (int it = 0; it < 4; ++it) {
        int cid = t + it * 256, row = cid >> 4, off = (cid & 15) << 3;
        *(u16x8*)&Bs[row * 136 + off] = *(const u16x8*)&Ah[(size_t)(q0 + row) * 128 + off];
    }
    if (t < 64) zf[t] = 0.f;
    __syncthreads();
    bf16x8 qfrag[8];
    {
        const unsigned short* ab = &Bs[(32 * qb + lm) * 136 + half * 8];
#pragma unroll
        for (int c = 0; c < 8; ++c) qfrag[c] = *(const bf16x8*)(ab + c * 16);
    }

    f32x16 oacc0 = {}, oacc1 = {};   // k-partial O: rows q (reg dim), dd = lm / 32+lm
    float zsum = 0.f;

    u16x8 pb[4], pv[2];
#pragma unroll
    for (int it = 0; it < 4; ++it) {
        int cid = t + it * 256, row = cid >> 4, off = (cid & 15) << 3;
        pb[it] = *(const u16x8*)&Bh[(size_t)row * 128 + off];
    }
#pragma unroll
    for (int it = 0; it < 2; ++it) {
        int cid = t + it * 256, row = cid >> 3, off = (cid & 7) << 3;
        pv[it] = *(const u16x8*)&Vh[(size_t)row * 2048 + off];
    }

    for (int kt = 0; kt <= qq; ++kt) {
        __syncthreads();   // b1: qfrag reads done (kt=0); prev tile's K/V reads done
#pragma unroll
        for (int it = 0; it < 4; ++it) {
            int cid = t + it * 256, row = cid >> 4, off = (cid & 15) << 3;
            *(u16x8*)&Bs[row * 136 + off] = pb[it];
        }
#pragma unroll
        for (int it = 0; it < 2; ++it) {
            int cid = t + it * 256, row = cid >> 3, off = (cid & 7) << 3;
            *(u16x8*)&Vs[row * 72 + off] = pv[it];
        }
        __syncthreads();   // b2: Bs/Vs visible
        if (kt < qq) {
            int k1 = (kt + 1) * 64;
#pragma unroll
            for (int it = 0; it < 4; ++it) {
                int cid = t + it * 256, row = cid >> 4, off = (cid & 15) << 3;
                pb[it] = *(const u16x8*)&Bh[(size_t)(k1 + row) * 128 + off];
            }
#pragma unroll
            for (int it = 0; it < 2; ++it) {
                int cid = t + it * 256, row = cid >> 3, off = (cid & 7) << 3;
                pv[it] = *(const u16x8*)&Vh[(size_t)row * 2048 + k1 + off];
            }
        }

        // S^T = K . Q^T : sacc reg r -> k_local=(r&3)+8*(r>>2)+4*half, q = lm
        f32x16 sacc = {};
        const unsigned short* kbase = &Bs[(32 * kb + lm) * 136 + half * 8];
        __builtin_amdgcn_s_setprio(1);
#pragma unroll
        for (int ks = 0; ks < 8; ++ks) {
            bf16x8 kf = *(const bf16x8*)(kbase + ks * 16);
            sacc = __builtin_amdgcn_mfma_f32_32x32x16_bf16(kf, qfrag[ks], sacc, 0, 0, 0);
        }
        __builtin_amdgcn_s_setprio(0);

        if (kt == qq) {   // causal mask: zero where k > q (within diagonal tile)
#pragma unroll
            for (int r = 0; r < 16; ++r) {
                int kl = (r & 3) + 8 * (r >> 2) + 4 * half;
                if ((32 * kb + kl) > (32 * qb + lm)) sacc[r] = 0.f;
            }
        }
#pragma unroll
        for (int r = 0; r < 16; ++r) zsum += fabsf(sacc[r]);

        // build PV A-frags in-register: pa[kc] covers k-chunk kc*16..+15 of
        // this wave's 32-k block. After plswap(A,C): A = word0, C = word2.
        union { u32x4 u; bf16x8 b; } pa0, pa1;
        {
            uint32_t A = pkbf(sacc[0], sacc[1]);
            uint32_t B = pkbf(sacc[2], sacc[3]);
            uint32_t C = pkbf(sacc[4], sacc[5]);
            uint32_t D = pkbf(sacc[6], sacc[7]);
            plswap(A, C);
            plswap(B, D);
            pa0.u = (u32x4){A, B, C, D};
            uint32_t E = pkbf(sacc[8], sacc[9]);
            uint32_t F = pkbf(sacc[10], sacc[11]);
            uint32_t G = pkbf(sacc[12], sacc[13]);
            uint32_t H = pkbf(sacc[14], sacc[15]);
            plswap(E, G);
            plswap(F, H);
            pa1.u = (u32x4){E, F, G, H};
        }

        // O_partial += P . V : A rows = q (lane lm), B rows = dd
        const unsigned short* v0 = &Vs[(size_t)lm * 72 + 32 * kb + half * 8];
        const unsigned short* v1 = &Vs[(size_t)(32 + lm) * 72 + 32 * kb + half * 8];
        __builtin_amdgcn_s_setprio(1);
        {
            bf16x8 vb00 = *(const bf16x8*)(v0);
            bf16x8 vb10 = *(const bf16x8*)(v1);
            oacc0 = __builtin_amdgcn_mfma_f32_32x32x16_bf16(pa0.b, vb00, oacc0, 0, 0, 0);
            oacc1 = __builtin_amdgcn_mfma_f32_32x32x16_bf16(pa0.b, vb10, oacc1, 0, 0, 0);
            bf16x8 vb01 = *(const bf16x8*)(v0 + 16);
            bf16x8 vb11 = *(const bf16x8*)(v1 + 16);
            oacc0 = __builtin_amdgcn_mfma_f32_32x32x16_bf16(pa1.b, vb01, oacc0, 0, 0, 0);
            oacc1 = __builtin_amdgcn_mfma_f32_32x32x16_bf16(pa1.b, vb11, oacc1, 0, 0, 0);
        }
        __builtin_amdgcn_s_setprio(0);
    }

    // z: q = 32*qb + lm is lane-local; both kb-halves contribute via atomics
    atomicAdd(&zf[32 * qb + lm], zsum);
    __syncthreads();   // zf complete; all K-frag reads of Bs done -> safe to overlay

    float* Os = (float*)Bs;   // 64 x 65 f32 = 16640 B <= 17408 B
    if (kb == 0) {
#pragma unroll
        for (int r = 0; r < 16; ++r) {
            int ql = (r & 3) + 8 * (r >> 2) + 4 * half;
            Os[(32 * qb + ql) * 65 + lm]      = oacc0[r];
            Os[(32 * qb + ql) * 65 + 32 + lm] = oacc1[r];
        }
    }
    __syncthreads();
    if (kb == 1) {
#pragma unroll
        for (int r = 0; r < 16; ++r) {
            int ql = (r & 3) + 8 * (r >> 2) + 4 * half;
            int q = q0 + 32 * qb + ql;
            float invz = 1.f / zf[32 * qb + ql];
            float o0 = (Os[(32 * qb + ql) * 65 + lm]      + oacc0[r]) * invz;
            float o1 = (Os[(32 * qb + ql) * 65 + 32 + lm] + oacc1[r]) * invz;
            size_t base = ((size_t)(n * 2048 + q)) * 512 + h * 64;
            out[base + lm]      = o0;
            out[base + 32 + lm] = o1;
        }
    }
}

extern "C" void kernel_launch(void* const* d_in, const int* in_sizes, int n_in,
                              void* d_out, int out_size, void* d_ws, size_t ws_size,
                              hipStream_t stream) {
    (void)in_sizes; (void)n_in; (void)out_size; (void)ws_size;
    const float* query = (const float*)d_in[0];
    const float* key   = (const float*)d_in[1];
    const float* Wq    = (const float*)d_in[2];
    const float* Wk    = (const float*)d_in[3];
    const float* Wv    = (const float*)d_in[4];
    const float* coef  = (const float*)d_in[5];
    const float* posw  = (const float*)d_in[6];
    const float* posb  = (const float*)d_in[7];

    unsigned short* Af  = (unsigned short*)d_ws;            // 8 MiB
    unsigned short* Bf  = Af + (size_t)16 * 2048 * 128;     // 8 MiB
    unsigned short* Vf  = Bf + (size_t)16 * 2048 * 128;     // 4 MiB
    unsigned short* Xqb = Vf + (size_t)16 * 64 * 2048;      // 4 MiB
    unsigned short* Xkb = Xqb + (size_t)4096 * 512;         // 4 MiB
    unsigned short* Wqb = Xkb + (size_t)4096 * 512;         // 0.5 MiB
    unsigned short* Wkb = Wqb + (size_t)512 * 512;          // 0.5 MiB
    unsigned short* Wvb = Wkb + (size_t)512 * 512;          // 0.5 MiB

    cvt_kernel<<<dim3(1024, 1, 5), 256, 0, stream>>>(
        query, key, Wq, Wk, Wv, Xqb, Xkb, Wqb, Wkb, Wvb);
    proj_kernel<<<dim3(4, 32, 3), 256, 0, stream>>>(
        Xqb, Xkb, Wqb, Wkb, Wvb, coef, posw, posb, Af, Bf, Vf);
    attn_kernel<<<dim3(512), 256, 0, stream>>>(
        Af, Bf, Vf, (float*)d_out);
}

// Round 5
// 128.336 us; speedup vs baseline: 1.1145x; 1.0364x over previous
//
#include <hip/hip_runtime.h>
#include <hip/hip_bf16.h>
#include <cstdint>

// N=2, L=2048, H=8, d=64, D=512. Inputs/outputs f32; features bf16 + MFMA.

typedef __bf16 bf16x8 __attribute__((ext_vector_type(8)));
typedef float f32x16 __attribute__((ext_vector_type(16)));
typedef unsigned short u16x8 __attribute__((ext_vector_type(8)));
typedef uint32_t u32x4 __attribute__((ext_vector_type(4)));

__device__ __forceinline__ unsigned short f2bfu(float f) {
    uint32_t u = __float_as_uint(f);
    uint32_t r = (u + 0x7fffu + ((u >> 16) & 1u)) >> 16;
    return (unsigned short)r;
}
__device__ __forceinline__ uint32_t cvt2(float a, float b) {
    __hip_bfloat162 h = __float22bfloat162_rn(make_float2(a, b));
    return *reinterpret_cast<uint32_t*>(&h);
}
__device__ __forceinline__ float softplusf(float x) {
    return fmaxf(x, 0.f) + __logf(1.f + __expf(-fabsf(x)));
}
// pack two f32 -> one u32 of 2 bf16 (src0 -> low half)
__device__ __forceinline__ uint32_t pkbf(float a, float b) {
    uint32_t d;
    asm("v_cvt_pk_bf16_f32 %0, %1, %2" : "=v"(d) : "v"(a), "v"(b));
    return d;
}
// v_permlane32_swap_b32: a[l>=32] <-> b[l-32]
__device__ __forceinline__ void plswap(uint32_t& a, uint32_t& b) {
    asm volatile("v_permlane32_swap_b32 %0, %1" : "+v"(a), "+v"(b));
}

// ---------------------------------------------------------------------------
// cvt: one-shot f32 -> bf16 of query/key/Wq/Wk/Wv. UNCHANGED (passed r3/r4).
// ---------------------------------------------------------------------------
__global__ __launch_bounds__(256) void cvt_kernel(
    const float* __restrict__ query, const float* __restrict__ key,
    const float* __restrict__ Wq, const float* __restrict__ Wk,
    const float* __restrict__ Wv,
    unsigned short* __restrict__ Xqb, unsigned short* __restrict__ Xkb,
    unsigned short* __restrict__ Wqb, unsigned short* __restrict__ Wkb,
    unsigned short* __restrict__ Wvb)
{
    const int z = blockIdx.z;
    const float* src;
    unsigned short* dst;
    int n8;
    if (z == 0)      { src = query; dst = Xqb; n8 = 4096 * 512 / 8; }
    else if (z == 1) { src = key;   dst = Xkb; n8 = 4096 * 512 / 8; }
    else if (z == 2) { src = Wq;    dst = Wqb; n8 = 512 * 512 / 8;  }
    else if (z == 3) { src = Wk;    dst = Wkb; n8 = 512 * 512 / 8;  }
    else             { src = Wv;    dst = Wvb; n8 = 512 * 512 / 8;  }
    int idx = blockIdx.x * 256 + threadIdx.x;
    if (idx >= n8) return;
    const float4* s = (const float4*)src + (size_t)idx * 2;
    float4 a = s[0], b = s[1];
    uint4 o;
    o.x = cvt2(a.x, a.y); o.y = cvt2(a.z, a.w);
    o.z = cvt2(b.x, b.y); o.w = cvt2(b.z, b.w);
    *(uint4*)&dst[(size_t)idx * 8] = o;
}

// ---------------------------------------------------------------------------
// proj v3: C[m][c] = X[m][:].W[c][:] (4096x512x512 per mode), bf16 in.
// 128x64 tiles -> grid (8,32,3) = 768 blocks = EXACTLY 3/CU, balanced
// (v2's 384 blocks = 1.5/CU left half the machine idle). LDS 27.6 KB ->
// 3 blocks co-resident = 12 waves/CU = 3/SIMD (v2: 1.5/SIMD) to hide the
// 8 barrier-fenced K-phases that dominate at short K. acc = 2 f32x16
// (32 regs, vs v2's 64) -> VGPR ~100, no spill risk.
// mode 0 -> Af[nh][l][128]; mode 1 -> Bf[nh][l][128]; mode 2 -> Vf[nh][dd][l]
// ---------------------------------------------------------------------------
__global__ __launch_bounds__(256) void proj_kernel(
    const unsigned short* __restrict__ Xqb, const unsigned short* __restrict__ Xkb,
    const unsigned short* __restrict__ Wqb, const unsigned short* __restrict__ Wkb,
    const unsigned short* __restrict__ Wvb, const float* __restrict__ coef,
    const float* __restrict__ posw, const float* __restrict__ posb,
    unsigned short* __restrict__ Af, unsigned short* __restrict__ Bf,
    unsigned short* __restrict__ Vf)
{
    const int mode = blockIdx.z;
    const int c0 = blockIdx.x * 64;    // 8 tiles
    const int m0 = blockIdx.y * 128;   // 32 tiles
    const unsigned short* X = (mode == 0) ? Xqb : Xkb;
    const unsigned short* W = (mode == 0) ? Wqb : (mode == 1 ? Wkb : Wvb);

    __shared__ __align__(16) char smem[(128 + 64) * 72 * 2];  // 27648 B
    unsigned short* Xs = (unsigned short*)smem;                   // [128][72]
    unsigned short* Ws = (unsigned short*)(smem + 128 * 72 * 2);  // [64][72]

    const int t = threadIdx.x;
    const int lane = t & 63, wv = t >> 6;
    const int lm = lane & 31, half = lane >> 5;
    const int wrow = wv >> 1, wcol = wv & 1;

    f32x16 acc[2] = {};

    // staging: X-tile 128x64 bf16 = 1024 u16x8 chunks (4/thread);
    //          W-tile  64x64 bf16 =  512 chunks (2/thread).
    u16x8 px[4], pw[2];
    {
#pragma unroll
        for (int it = 0; it < 4; ++it) {
            int cid = t + it * 256, row = cid >> 3, seg = cid & 7;
            px[it] = *(const u16x8*)&X[(size_t)(m0 + row) * 512 + seg * 8];
        }
#pragma unroll
        for (int it = 0; it < 2; ++it) {
            int cid = t + it * 256, row = cid >> 3, seg = cid & 7;
            pw[it] = *(const u16x8*)&W[(size_t)(c0 + row) * 512 + seg * 8];
        }
    }

    for (int kt = 0; kt < 8; ++kt) {
        __syncthreads();
#pragma unroll
        for (int it = 0; it < 4; ++it) {
            int cid = t + it * 256, row = cid >> 3, seg = cid & 7;
            *(u16x8*)&Xs[row * 72 + seg * 8] = px[it];
        }
#pragma unroll
        for (int it = 0; it < 2; ++it) {
            int cid = t + it * 256, row = cid >> 3, seg = cid & 7;
            *(u16x8*)&Ws[row * 72 + seg * 8] = pw[it];
        }
        __syncthreads();
        if (kt < 7) {
            int ko = (kt + 1) * 64;
#pragma unroll
            for (int it = 0; it < 4; ++it) {
                int cid = t + it * 256, row = cid >> 3, seg = cid & 7;
                px[it] = *(const u16x8*)&X[(size_t)(m0 + row) * 512 + ko + seg * 8];
            }
#pragma unroll
            for (int it = 0; it < 2; ++it) {
                int cid = t + it * 256, row = cid >> 3, seg = cid & 7;
                pw[it] = *(const u16x8*)&W[(size_t)(c0 + row) * 512 + ko + seg * 8];
            }
        }
        const unsigned short* ab = &Xs[(64 * wrow + lm) * 72 + half * 8];
        const unsigned short* bb = &Ws[(32 * wcol + lm) * 72 + half * 8];
        __builtin_amdgcn_s_setprio(1);
#pragma unroll
        for (int ks = 0; ks < 4; ++ks) {
            bf16x8 a0 = *(const bf16x8*)(ab + ks * 16);
            bf16x8 a1 = *(const bf16x8*)(ab + 32 * 72 + ks * 16);
            bf16x8 b  = *(const bf16x8*)(bb + ks * 16);
            acc[0] = __builtin_amdgcn_mfma_f32_32x32x16_bf16(a0, b, acc[0], 0, 0, 0);
            acc[1] = __builtin_amdgcn_mfma_f32_32x32x16_bf16(a1, b, acc[1], 0, 0, 0);
        }
        __builtin_amdgcn_s_setprio(0);
    }

    if (mode != 2) {
        unsigned short* Feat = (mode == 0) ? Af : Bf;
        int c = c0 + 32 * wcol + lm;
        int h = c >> 6, jj = c & 63;
        float wgt = posw[c];
        float bia = (mode == 0) ? posb[c] : 0.f;
        float cf  = (mode == 1) ? coef[c] : 1.f;
#pragma unroll
        for (int i = 0; i < 2; ++i)
#pragma unroll
        for (int r = 0; r < 16; ++r) {
            int rl = (r & 3) + 8 * (r >> 2) + 4 * half;
            int m = m0 + 64 * wrow + 32 * i + rl;
            int n = m >> 11, l = m & 2047;
            float ang = (float)l * wgt + bia;
            float sn, cs; __sincosf(ang, &sn, &cs);
            float v = softplusf(acc[i][r]) * cf;
            size_t base = ((size_t)(n * 8 + h) * 2048 + l) * 128 + jj;
            Feat[base]      = f2bfu(v * cs);
            Feat[base + 64] = f2bfu(v * sn);
        }
    } else {
        // transpose through LDS; per-wave private 32x34 f32 buffer overlays
        // smem (4 waves * 4352 B = 17408 B <= 27648 B). Within-wave
        // write->read lockstep (v1/v2-proven pattern); one entry sync
        // protects the overlay vs other waves' final MFMA reads.
        float* tb = (float*)smem;
        float* tbw = tb + wv * (32 * 34);
        __syncthreads();
#pragma unroll
        for (int i = 0; i < 2; ++i) {
#pragma unroll
            for (int r = 0; r < 16; ++r) {
                int rl = (r & 3) + 8 * (r >> 2) + 4 * half;
                tbw[lm * 34 + rl] = acc[i][r];
            }
            int mb = m0 + 64 * wrow + 32 * i;
            int n = mb >> 11, l0 = mb & 2047;
#pragma unroll
            for (int rep = 0; rep < 16; ++rep) {
                int cl = rep * 2 + half;
                float v = tbw[cl * 34 + lm];
                int c = c0 + 32 * wcol + cl;
                int h = c >> 6, dd = c & 63;
                Vf[((size_t)(n * 8 + h) * 64 + dd) * 2048 + l0 + lm] = f2bfu(v);
            }
        }
    }
}

// ---------------------------------------------------------------------------
// attn v2: swapped QK^T (T12), in-register P via cvt_pk+permlane32_swap.
// UNCHANGED from round 4 (passed, ~33.5 us).
// ---------------------------------------------------------------------------
__global__ __launch_bounds__(256) void attn_kernel(
    const unsigned short* __restrict__ Af, const unsigned short* __restrict__ Bf,
    const unsigned short* __restrict__ Vf, float* __restrict__ out)
{
    const int bx = blockIdx.x;
    const int nh = bx & 15;
    const int p  = bx >> 4;
    const int qq = (p < 16) ? p : 47 - p;   // bx and bx+256 complementary
    const int q0 = qq * 64;

    __shared__ unsigned short Bs[64 * 136];   // K-features; Q-stage at init; O-merge overlay at end
    __shared__ unsigned short Vs[64 * 72];    // V [dd][k]
    __shared__ float zf[64];

    const int t = threadIdx.x;
    const int lane = t & 63, wv = t >> 6;
    const int lm = lane & 31, half = lane >> 5;
    const int qb = wv >> 1, kb = wv & 1;
    const int n = nh >> 3, h = nh & 7;

    const unsigned short* Ah = Af + (size_t)nh * 2048 * 128;
    const unsigned short* Bh = Bf + (size_t)nh * 2048 * 128;
    const unsigned short* Vh = Vf + (size_t)nh * 64 * 2048;

#pragma unroll
    for (int it = 0; it < 4; ++it) {
        int cid = t + it * 256, row = cid >> 4, off = (cid & 15) << 3;
        *(u16x8*)&Bs[row * 136 + off] = *(const u16x8*)&Ah[(size_t)(q0 + row) * 128 + off];
    }
    if (t < 64) zf[t] = 0.f;
    __syncthreads();
    bf16x8 qfrag[8];
    {
        const unsigned short* ab = &Bs[(32 * qb + lm) * 136 + half * 8];
#pragma unroll
        for (int c = 0; c < 8; ++c) qfrag[c] = *(const bf16x8*)(ab + c * 16);
    }

    f32x16 oacc0 = {}, oacc1 = {};
    float zsum = 0.f;

    u16x8 pb[4], pv[2];
#pragma unroll
    for (int it = 0; it < 4; ++it) {
        int cid = t + it * 256, row = cid >> 4, off = (cid & 15) << 3;
        pb[it] = *(const u16x8*)&Bh[(size_t)row * 128 + off];
    }
#pragma unroll
    for (int it = 0; it < 2; ++it) {
        int cid = t + it * 256, row = cid >> 3, off = (cid & 7) << 3;
        pv[it] = *(const u16x8*)&Vh[(size_t)row * 2048 + off];
    }

    for (int kt = 0; kt <= qq; ++kt) {
        __syncthreads();
#pragma unroll
        for (int it = 0; it < 4; ++it) {
            int cid = t + it * 256, row = cid >> 4, off = (cid & 15) << 3;
            *(u16x8*)&Bs[row * 136 + off] = pb[it];
        }
#pragma unroll
        for (int it = 0; it < 2; ++it) {
            int cid = t + it * 256, row = cid >> 3, off = (cid & 7) << 3;
            *(u16x8*)&Vs[row * 72 + off] = pv[it];
        }
        __syncthreads();
        if (kt < qq) {
            int k1 = (kt + 1) * 64;
#pragma unroll
            for (int it = 0; it < 4; ++it) {
                int cid = t + it * 256, row = cid >> 4, off = (cid & 15) << 3;
                pb[it] = *(const u16x8*)&Bh[(size_t)(k1 + row) * 128 + off];
            }
#pragma unroll
            for (int it = 0; it < 2; ++it) {
                int cid = t + it * 256, row = cid >> 3, off = (cid & 7) << 3;
                pv[it] = *(const u16x8*)&Vh[(size_t)row * 2048 + k1 + off];
            }
        }

        f32x16 sacc = {};
        const unsigned short* kbase = &Bs[(32 * kb + lm) * 136 + half * 8];
        __builtin_amdgcn_s_setprio(1);
#pragma unroll
        for (int ks = 0; ks < 8; ++ks) {
            bf16x8 kf = *(const bf16x8*)(kbase + ks * 16);
            sacc = __builtin_amdgcn_mfma_f32_32x32x16_bf16(kf, qfrag[ks], sacc, 0, 0, 0);
        }
        __builtin_amdgcn_s_setprio(0);

        if (kt == qq) {
#pragma unroll
            for (int r = 0; r < 16; ++r) {
                int kl = (r & 3) + 8 * (r >> 2) + 4 * half;
                if ((32 * kb + kl) > (32 * qb + lm)) sacc[r] = 0.f;
            }
        }
#pragma unroll
        for (int r = 0; r < 16; ++r) zsum += fabsf(sacc[r]);

        union { u32x4 u; bf16x8 b; } pa0, pa1;
        {
            uint32_t A = pkbf(sacc[0], sacc[1]);
            uint32_t B = pkbf(sacc[2], sacc[3]);
            uint32_t C = pkbf(sacc[4], sacc[5]);
            uint32_t D = pkbf(sacc[6], sacc[7]);
            plswap(A, C);
            plswap(B, D);
            pa0.u = (u32x4){A, B, C, D};
            uint32_t E = pkbf(sacc[8], sacc[9]);
            uint32_t F = pkbf(sacc[10], sacc[11]);
            uint32_t G = pkbf(sacc[12], sacc[13]);
            uint32_t H = pkbf(sacc[14], sacc[15]);
            plswap(E, G);
            plswap(F, H);
            pa1.u = (u32x4){E, F, G, H};
        }

        const unsigned short* v0 = &Vs[(size_t)lm * 72 + 32 * kb + half * 8];
        const unsigned short* v1 = &Vs[(size_t)(32 + lm) * 72 + 32 * kb + half * 8];
        __builtin_amdgcn_s_setprio(1);
        {
            bf16x8 vb00 = *(const bf16x8*)(v0);
            bf16x8 vb10 = *(const bf16x8*)(v1);
            oacc0 = __builtin_amdgcn_mfma_f32_32x32x16_bf16(pa0.b, vb00, oacc0, 0, 0, 0);
            oacc1 = __builtin_amdgcn_mfma_f32_32x32x16_bf16(pa0.b, vb10, oacc1, 0, 0, 0);
            bf16x8 vb01 = *(const bf16x8*)(v0 + 16);
            bf16x8 vb11 = *(const bf16x8*)(v1 + 16);
            oacc0 = __builtin_amdgcn_mfma_f32_32x32x16_bf16(pa1.b, vb01, oacc0, 0, 0, 0);
            oacc1 = __builtin_amdgcn_mfma_f32_32x32x16_bf16(pa1.b, vb11, oacc1, 0, 0, 0);
        }
        __builtin_amdgcn_s_setprio(0);
    }

    atomicAdd(&zf[32 * qb + lm], zsum);
    __syncthreads();

    float* Os = (float*)Bs;
    if (kb == 0) {
#pragma unroll
        for (int r = 0; r < 16; ++r) {
            int ql = (r & 3) + 8 * (r >> 2) + 4 * half;
            Os[(32 * qb + ql) * 65 + lm]      = oacc0[r];
            Os[(32 * qb + ql) * 65 + 32 + lm] = oacc1[r];
        }
    }
    __syncthreads();
    if (kb == 1) {
#pragma unroll
        for (int r = 0; r < 16; ++r) {
            int ql = (r & 3) + 8 * (r >> 2) + 4 * half;
            int q = q0 + 32 * qb + ql;
            float invz = 1.f / zf[32 * qb + ql];
            float o0 = (Os[(32 * qb + ql) * 65 + lm]      + oacc0[r]) * invz;
            float o1 = (Os[(32 * qb + ql) * 65 + 32 + lm] + oacc1[r]) * invz;
            size_t base = ((size_t)(n * 2048 + q)) * 512 + h * 64;
            out[base + lm]      = o0;
            out[base + 32 + lm] = o1;
        }
    }
}

extern "C" void kernel_launch(void* const* d_in, const int* in_sizes, int n_in,
                              void* d_out, int out_size, void* d_ws, size_t ws_size,
                              hipStream_t stream) {
    (void)in_sizes; (void)n_in; (void)out_size; (void)ws_size;
    const float* query = (const float*)d_in[0];
    const float* key   = (const float*)d_in[1];
    const float* Wq    = (const float*)d_in[2];
    const float* Wk    = (const float*)d_in[3];
    const float* Wv    = (const float*)d_in[4];
    const float* coef  = (const float*)d_in[5];
    const float* posw  = (const float*)d_in[6];
    const float* posb  = (const float*)d_in[7];

    unsigned short* Af  = (unsigned short*)d_ws;            // 8 MiB
    unsigned short* Bf  = Af + (size_t)16 * 2048 * 128;     // 8 MiB
    unsigned short* Vf  = Bf + (size_t)16 * 2048 * 128;     // 4 MiB
    unsigned short* Xqb = Vf + (size_t)16 * 64 * 2048;      // 4 MiB
    unsigned short* Xkb = Xqb + (size_t)4096 * 512;         // 4 MiB
    unsigned short* Wqb = Xkb + (size_t)4096 * 512;         // 0.5 MiB
    unsigned short* Wkb = Wqb + (size_t)512 * 512;          // 0.5 MiB
    unsigned short* Wvb = Wkb + (size_t)512 * 512;          // 0.5 MiB

    cvt_kernel<<<dim3(1024, 1, 5), 256, 0, stream>>>(
        query, key, Wq, Wk, Wv, Xqb, Xkb, Wqb, Wkb, Wvb);
    proj_kernel<<<dim3(8, 32, 3), 256, 0, stream>>>(
        Xqb, Xkb, Wqb, Wkb, Wvb, coef, posw, posb, Af, Bf, Vf);
    attn_kernel<<<dim3(512), 256, 0, stream>>>(
        Af, Bf, Vf, (float*)d_out);
}